// Round 9
// baseline (293.668 us; speedup 1.0000x reference)
//
#include <hip/hip_runtime.h>
#include <hip/hip_bf16.h>

typedef __hip_bfloat16 bf16;
typedef short bf16x8 __attribute__((ext_vector_type(8)));
typedef float f32x4 __attribute__((ext_vector_type(4)));

#define MFMA16(a,b,c) __builtin_amdgcn_mfma_f32_16x16x32_bf16(a,b,c,0,0,0)

__device__ __forceinline__ unsigned short f2us(float x){
    union{__hip_bfloat16 h; unsigned short u;} c; c.h = __float2bfloat16(x); return c.u;
}
__device__ __forceinline__ float us2f(unsigned short u){
    union{unsigned short u; __hip_bfloat16 h;} c; c.u = u; return __bfloat162float(c.h);
}
__device__ __forceinline__ uint4 pack8(float4 a, float4 b){
    union{unsigned short us[8]; uint4 v;} p;
    p.us[0]=f2us(a.x); p.us[1]=f2us(a.y); p.us[2]=f2us(a.z); p.us[3]=f2us(a.w);
    p.us[4]=f2us(b.x); p.us[5]=f2us(b.y); p.us[6]=f2us(b.z); p.us[7]=f2us(b.w);
    return p.v;
}

// ---------------------------------------------------------------------------
// fused: prep (weight transposes, distributed across the 256 blocks) ->
// device semaphore (all blocks co-resident: 147K LDS = 1 block/CU, grid 256
// on 256 CUs) -> qkav body (round-6 form, measured 180.6 us, no prefetch /
// plain __syncthreads — register-prefetch is twice-falsified by spill).
// Semaphore protocol (G16): producers __syncthreads (stores drained to L2),
// tid0 __threadfence (XCD L2 writeback) + device-scope release add; spin on
// device-scope acquire load; __threadfence (invalidate); __syncthreads.
// Counter zeroed via hipMemsetAsync node before the kernel.
// ---------------------------------------------------------------------------
__global__ __launch_bounds__(512, 2) void fused_kernel(
    const float* __restrict__ Qin, const float* __restrict__ Kin,
    const float* __restrict__ Vin, const int* __restrict__ mask,
    const float* __restrict__ Wq, const float* __restrict__ bq,
    const float* __restrict__ Wk, const float* __restrict__ bk,
    const float* __restrict__ Wv, const float* __restrict__ bv,
    const float* __restrict__ Wo, const float* __restrict__ bo,
    bf16* __restrict__ WqT, bf16* __restrict__ WkT, bf16* __restrict__ WvT,
    float* __restrict__ bqp, float* __restrict__ bkp, float* __restrict__ bvp,
    bf16* __restrict__ WoT, unsigned int* __restrict__ cnt,
    float* __restrict__ Out)
{
    __shared__ __align__(16) char smem[147456];
    const int tid = threadIdx.x;
    const int bx  = blockIdx.x;

    // ================= prep phase: this block's units ===================
    // unit u in [0,515): u<384 -> W-tile (mat=u/128), 384..386 -> bias,
    // u>=387 -> Wo-tile. Block b runs units {b, b+256} and, for b<3, b+512.
    {
        float (*T)[68] = (float (*)[68])smem;
        #pragma unroll 1
        for (int ui = 0; ui < 3; ++ui) {
            if (ui == 2 && bx >= 3) break;
            const int u = bx + (ui << 8);
            if (u < 384) {
                const int mat = u / 128, rem = u % 128;
                const int c0 = (rem >> 5) * 64, n0 = (rem & 31) * 64;
                const float* W = (mat == 0) ? Wq : (mat == 1) ? Wk : Wv;
                bf16* WT = (mat == 0) ? WqT : (mat == 1) ? WkT : WvT;
                #pragma unroll
                for (int it = 0; it < 2; ++it) {
                    int pp = tid + (it << 9);
                    int cl = pp >> 4, n4 = (pp & 15) * 4;
                    float4 f = *(const float4*)(W + (size_t)(c0 + cl) * 2048 + n0 + n4);
                    T[cl][n4] = f.x; T[cl][n4+1] = f.y; T[cl][n4+2] = f.z; T[cl][n4+3] = f.w;
                }
                __syncthreads();
                const int h = n0 >> 8, d0 = n0 & 255;
                {
                    int j = tid >> 3, g = tid & 7;
                    union{unsigned short us[8]; uint4 v;} pk;
                    #pragma unroll
                    for (int u2 = 0; u2 < 8; ++u2) pk.us[u2] = f2us(T[g*8+u2][j]);
                    *(uint4*)(WT + (size_t)((d0 + j) * 8 + h) * 256 + c0 + g * 8) = pk.v;
                }
                __syncthreads();
            } else if (u < 387) {
                const int mat = u - 384;
                const float* src = (mat == 0) ? bq : (mat == 1) ? bk : bv;
                float* dst = (mat == 0) ? bqp : (mat == 1) ? bkp : bvp;
                for (int n = tid; n < 2048; n += 512)
                    dst[(n & 255) * 8 + (n >> 8)] = src[n];
                __syncthreads();
            } else {
                const int idx = u - 387;
                const int k0 = (idx >> 2) * 64, c0 = (idx & 3) * 64;
                #pragma unroll
                for (int it = 0; it < 2; ++it) {
                    int pp = tid + (it << 9);
                    int kl = pp >> 4, c4 = (pp & 15) * 4;
                    float4 f = *(const float4*)(Wo + (size_t)(k0 + kl) * 256 + c0 + c4);
                    T[kl][c4] = f.x; T[kl][c4+1] = f.y; T[kl][c4+2] = f.z; T[kl][c4+3] = f.w;
                }
                __syncthreads();
                {
                    int j = tid >> 3, g = tid & 7;
                    union{unsigned short us[8]; uint4 v;} pk;
                    #pragma unroll
                    for (int u2 = 0; u2 < 8; ++u2) pk.us[u2] = f2us(T[g*8+u2][j]);
                    *(uint4*)(WoT + (size_t)(c0 + j) * 2048 + k0 + g * 8) = pk.v;
                }
                __syncthreads();
            }
        }
    }

    // ================= grid semaphore ===================================
    __syncthreads();                    // all this block's stores drained to L2
    if (tid == 0) {
        __threadfence();                // XCD L2 writeback (device visibility)
        __hip_atomic_fetch_add(cnt, 1u, __ATOMIC_RELEASE, __HIP_MEMORY_SCOPE_AGENT);
        while (__hip_atomic_load(cnt, __ATOMIC_ACQUIRE, __HIP_MEMORY_SCOPE_AGENT) < 256u)
            __builtin_amdgcn_s_sleep(8);
        __threadfence();                // invalidate before reading others' data
    }
    __syncthreads();

    // ================= qkav body (round-6 form) =========================
    // phase 1 aliases
    char* const Xq = smem;
    char* const Xk = smem + 32768;
    char* const QT = smem + 65536;
    char* const KT = smem + 106496;
    float* const RED  = (float*)smem;            // [64][68] over Xq
    float* const WLDS = (float*)(smem + 106496); // [64][68] over KT (later)
    // phase 2 aliases
    char* const Xv  = smem;
    char* const VT0 = smem + 32768;
    char* const VT1 = smem + 50176;
    char* const xS0 = smem + 67584;
    char* const xS1 = smem + 83968;

    const int wid  = tid >> 6, lane = tid & 63;
    const int quad = lane >> 4, l15 = lane & 15;
    const int tok0 = bx * 64;
    const int t6   = tid & 63, dg = tid >> 6;

    // ---------------- phase 1: Q/K projection + scores -----------------
    #pragma unroll
    for (int it = 0; it < 4; ++it) {
        int pp = tid + (it << 9);
        int row = pp >> 5, g = pp & 31;
        const float* s = Qin + (size_t)(tok0 + row) * 256 + g * 8;
        *(uint4*)(Xq + row * 512 + ((g ^ (row & 7)) << 4)) =
            pack8(*(const float4*)s, *(const float4*)(s + 4));
        s = Kin + (size_t)(tok0 + row) * 256 + g * 8;
        *(uint4*)(Xk + row * 512 + ((g ^ (row & 7)) << 4)) =
            pack8(*(const float4*)s, *(const float4*)(s + 4));
    }
    __syncthreads();

    f32x4 sacc[4];
    #pragma unroll
    for (int p = 0; p < 4; ++p)
        #pragma unroll
        for (int i = 0; i < 4; ++i) sacc[p][i] = 0.f;

    for (int Cp = 0; Cp < 8; ++Cp) {
        f32x4 accq[4][2], acck[4][2];
        #pragma unroll
        for (int mt = 0; mt < 4; ++mt)
            #pragma unroll
            for (int nt = 0; nt < 2; ++nt)
                #pragma unroll
                for (int i = 0; i < 4; ++i) { accq[mt][nt][i] = 0.f; acck[mt][nt][i] = 0.f; }
        #pragma unroll
        for (int Ks = 0; Ks < 8; ++Ks) {
            bf16x8 bqf[2], bkf[2];
            #pragma unroll
            for (int nt = 0; nt < 2; ++nt) {
                const size_t boff =
                    (size_t)(Cp * 256 + wid * 32 + nt * 16 + l15) * 256 + Ks * 32 + quad * 8;
                bqf[nt] = *(const bf16x8*)(WqT + boff);
                bkf[nt] = *(const bf16x8*)(WkT + boff);
            }
            #pragma unroll
            for (int mt = 0; mt < 4; ++mt) {
                int row = mt * 16 + l15;
                int G = (Ks * 4 + quad) ^ (row & 7);
                bf16x8 aq = *(const bf16x8*)(Xq + row * 512 + (G << 4));
                bf16x8 ak = *(const bf16x8*)(Xk + row * 512 + (G << 4));
                #pragma unroll
                for (int nt = 0; nt < 2; ++nt) {
                    accq[mt][nt] = MFMA16(aq, bqf[nt], accq[mt][nt]);
                    acck[mt][nt] = MFMA16(ak, bkf[nt], acck[mt][nt]);
                }
            }
        }
        #pragma unroll
        for (int nt = 0; nt < 2; ++nt) {
            const int p2 = wid * 32 + nt * 16 + l15;
            const int rowoff = p2 * 160 + ((p2 >> 6) & 3) * 8;
            const float biq = bqp[Cp * 256 + p2];
            const float bik = bkp[Cp * 256 + p2];
            #pragma unroll
            for (int mt = 0; mt < 4; ++mt) {
                int t0 = mt * 16 + quad * 4;
                union{unsigned short us[4]; uint2 v;} pq, pk;
                #pragma unroll
                for (int i = 0; i < 4; ++i) {
                    pq.us[i] = f2us(accq[mt][nt][i] + biq);
                    pk.us[i] = f2us(acck[mt][nt][i] + bik);
                }
                *(uint2*)(QT + rowoff + t0 * 2) = pq.v;
                *(uint2*)(KT + rowoff + t0 * 2) = pk.v;
            }
        }
        __syncthreads();
        #pragma unroll
        for (int pp2 = 0; pp2 < 4; ++pp2) {
            int tq = 2 * (wid * 4 + pp2) + (l15 >> 3);
            union{unsigned short us[8]; bf16x8 v;} Aq, Bk;
            #pragma unroll
            for (int j = 0; j < 8; ++j) {
                int p2 = (quad * 8 + j) * 8 + (l15 & 7);
                int off = p2 * 160 + ((p2 >> 6) & 3) * 8 + tq * 2;
                Aq.us[j] = *(const unsigned short*)(QT + off);
                Bk.us[j] = *(const unsigned short*)(KT + off);
            }
            sacc[pp2] = MFMA16(Aq.v, Bk.v, sacc[pp2]);
        }
        __syncthreads();
    }

    // diagonal extraction -> RED[t][h*8+g]  (Xq dead, KT dead)
    if ((quad >> 1) == (l15 >> 3)) {
        #pragma unroll
        for (int pp2 = 0; pp2 < 4; ++pp2) {
            int tl = (wid * 4 + pp2) * 2 + (l15 >> 3);
            #pragma unroll
            for (int i = 0; i < 4; ++i)
                RED[tl * 68 + ((quad & 1) * 4 + i) * 8 + (l15 & 7)] = sacc[pp2][i];
        }
    }
    __syncthreads();
    // softmax: thread (tl, h) -> WLDS
    {
        const int tl = tid >> 3, hh = tid & 7;
        const int mk = mask[tok0 + tl];
        const float* r = RED + tl * 68 + hh * 8;
        float m = r[0];
        #pragma unroll
        for (int g = 1; g < 8; ++g) m = fmaxf(m, r[g]);
        float e[8], sum = 0.f;
        #pragma unroll
        for (int g = 0; g < 8; ++g) { e[g] = __expf((r[g] - m) * 0.0625f); sum += e[g]; }
        float inv = 1.f / sum;
        float o[8];
        #pragma unroll
        for (int g = 0; g < 8; ++g) o[g] = mk ? e[g] * inv : 0.125f;
        float* wp = WLDS + tl * 68 + hh * 8;
        *(float4*)wp = make_float4(o[0], o[1], o[2], o[3]);
        *(float4*)(wp + 4) = make_float4(o[4], o[5], o[6], o[7]);
    }
    __syncthreads();   // WLDS visible; RED fully read before Xv overwrite

    // ---------------- phase 2: V projection + wsum + out-proj ----------
    float wv[64];
    {
        const float* wl = WLDS + t6 * 68;
        #pragma unroll
        for (int i = 0; i < 16; ++i) {
            float4 f = *(const float4*)(wl + i * 4);
            wv[i*4] = f.x; wv[i*4+1] = f.y; wv[i*4+2] = f.z; wv[i*4+3] = f.w;
        }
    }
    #pragma unroll
    for (int it = 0; it < 4; ++it) {
        int pp = tid + (it << 9);
        int row = pp >> 5, g = pp & 31;
        const float* s = Vin + (size_t)(tok0 + row) * 256 + g * 8;
        *(uint4*)(Xv + row * 512 + ((g ^ (row & 7)) << 4)) =
            pack8(*(const float4*)s, *(const float4*)(s + 4));
    }
    __syncthreads();

    const int pll = wid * 16 + l15;

    f32x4 oacc[4][2];
    #pragma unroll
    for (int mt = 0; mt < 4; ++mt)
        #pragma unroll
        for (int nt = 0; nt < 2; ++nt)
            #pragma unroll
            for (int i = 0; i < 4; ++i) oacc[mt][nt][i] = 0.f;

    for (int p = 0; p < 18; ++p) {
        char* const VTw = (p & 1) ? VT1 : VT0;
        char* const VTr = (p & 1) ? VT0 : VT1;
        char* const xSw = (p & 1) ? xS0 : xS1;
        char* const xSr = (p & 1) ? xS1 : xS0;

        // --- stream 1: v-proj for chunk C = p ---
        if (p < 16) {
            const int C = p;
            f32x4 acc[4];
            #pragma unroll
            for (int mt = 0; mt < 4; ++mt)
                #pragma unroll
                for (int i = 0; i < 4; ++i) acc[mt][i] = 0.f;
            #pragma unroll
            for (int Ks = 0; Ks < 8; ++Ks) {
                bf16x8 b = *(const bf16x8*)(WvT + (size_t)(C * 128 + pll) * 256 + Ks * 32 + quad * 8);
                #pragma unroll
                for (int mt = 0; mt < 4; ++mt) {
                    int row = mt * 16 + l15;
                    int G = (Ks * 4 + quad) ^ (row & 7);
                    bf16x8 a = *(const bf16x8*)(Xv + row * 512 + (G << 4));
                    acc[mt] = MFMA16(a, b, acc[mt]);
                }
            }
            const float biv = bvp[C * 128 + pll];
            #pragma unroll
            for (int mt = 0; mt < 4; ++mt) {
                int t0 = mt * 16 + quad * 4;
                union{unsigned short us[4]; uint2 v;} pk;
                #pragma unroll
                for (int i = 0; i < 4; ++i) pk.us[i] = f2us(acc[mt][i] + biv);
                *(uint2*)(VTw + pll * 136 + t0 * 2) = pk.v;
            }
        }

        // --- stream 2: weighted sum for chunk C = p-1 (VALU pipe) ---
        if (p >= 1 && p <= 16) {
            #pragma unroll
            for (int dd = 0; dd < 2; ++dd) {
                int d = dg * 2 + dd;
                float vv[8];
                #pragma unroll
                for (int g = 0; g < 8; ++g)
                    vv[g] = us2f(*(const unsigned short*)(VTr + (d * 8 + g) * 136 + t6 * 2));
                #pragma unroll
                for (int h = 0; h < 8; ++h) {
                    float x = 0.f;
                    #pragma unroll
                    for (int g = 0; g < 8; ++g) x = fmaf(wv[h * 8 + g], vv[g], x);
                    int u = (h * 2 + (d >> 3)) ^ (t6 & 15);
                    *(unsigned short*)(xSw + t6 * 256 + u * 16 + (d & 7) * 2) = f2us(x);
                }
            }
        }

        // --- stream 3: out-proj accumulate for chunk C = p-2 ---
        if (p >= 2) {
            const int C = p - 2;
            #pragma unroll
            for (int m = 0; m < 4; ++m) {
                const int j  = 2 * m + (quad >> 1);
                const int k0 = j * 256 + C * 16 + (quad & 1) * 8;
                bf16x8 bfr[2];
                #pragma unroll
                for (int nt = 0; nt < 2; ++nt) {
                    int c = wid * 32 + nt * 16 + l15;
                    bfr[nt] = *(const bf16x8*)(WoT + (size_t)c * 2048 + k0);
                }
                #pragma unroll
                for (int mt = 0; mt < 4; ++mt) {
                    int h = mt * 2 + (l15 >> 3);
                    int t = (l15 & 7) * 8 + j;
                    int u = (h * 2 + (quad & 1)) ^ (t & 15);
                    bf16x8 afr = *(const bf16x8*)(xSr + t * 256 + u * 16);
                    #pragma unroll
                    for (int nt = 0; nt < 2; ++nt)
                        oacc[mt][nt] = MFMA16(afr, bfr[nt], oacc[mt][nt]);
                }
            }
        }

        __syncthreads();
    }

    // epilogue: bias + direct Out write (reference's transpose-reshape rows)
    const int b = tok0 >> 11, sg0 = (tok0 & 2047) >> 3;
    #pragma unroll
    for (int nt = 0; nt < 2; ++nt) {
        int c = wid * 32 + nt * 16 + l15;
        float bias = bo[c];
        #pragma unroll
        for (int mt = 0; mt < 4; ++mt) {
            #pragma unroll
            for (int i = 0; i < 4; ++i) {
                int rr = mt * 16 + quad * 4 + i;
                int h = rr >> 3, sgl = rr & 7;
                size_t r = ((size_t)b << 11) + h * 256 + sg0 + sgl;
                Out[r * 256 + c] = oacc[mt][nt][i] + bias;
            }
        }
    }
}

// ---------------------------------------------------------------------------
extern "C" void kernel_launch(void* const* d_in, const int* in_sizes, int n_in,
                              void* d_out, int out_size, void* d_ws, size_t ws_size,
                              hipStream_t stream) {
    const float* query = (const float*)d_in[0];
    const float* key   = (const float*)d_in[1];
    const float* value = (const float*)d_in[2];
    const int*   mask  = (const int*)  d_in[3];
    const float* Wq = (const float*)d_in[4];  const float* bq = (const float*)d_in[5];
    const float* Wk = (const float*)d_in[6];  const float* bk = (const float*)d_in[7];
    const float* Wv = (const float*)d_in[8];  const float* bv = (const float*)d_in[9];
    const float* Wo = (const float*)d_in[10]; const float* bo = (const float*)d_in[11];

    // scratch in d_ws:
    char* ws = (char*)d_ws;
    bf16*  WoT = (bf16*)ws;                    // [256 c][2048 k] bf16, 1 MB
    bf16*  WqT = (bf16*)(ws + 1048576);        // [2048][256] bf16, 1 MB each
    bf16*  WkT = (bf16*)(ws + 2097152);
    bf16*  WvT = (bf16*)(ws + 3145728);
    float* bqp = (float*)(ws + 4194304);
    float* bkp = (float*)(ws + 4202496);
    float* bvp = (float*)(ws + 4210688);
    unsigned int* cnt = (unsigned int*)(ws + 4218880);

    hipMemsetAsync(cnt, 0, 16, stream);        // zero semaphore (graph-legal)
    fused_kernel<<<256, 512, 0, stream>>>(
        query, key, value, mask, Wq, bq, Wk, bk, Wv, bv, Wo, bo,
        WqT, WkT, WvT, bqp, bkp, bvp, WoT, cnt, (float*)d_out);
}

// Round 10
// 268.702 us; speedup vs baseline: 1.0929x; 1.0929x over previous
//
#include <hip/hip_runtime.h>
#include <hip/hip_bf16.h>

typedef __hip_bfloat16 bf16;
typedef short bf16x8 __attribute__((ext_vector_type(8)));
typedef float f32x4 __attribute__((ext_vector_type(4)));

#define MFMA16(a,b,c) __builtin_amdgcn_mfma_f32_16x16x32_bf16(a,b,c,0,0,0)

__device__ __forceinline__ unsigned short f2us(float x){
    union{__hip_bfloat16 h; unsigned short u;} c; c.h = __float2bfloat16(x); return c.u;
}
__device__ __forceinline__ float us2f(unsigned short u){
    union{unsigned short u; __hip_bfloat16 h;} c; c.u = u; return __bfloat162float(c.h);
}
__device__ __forceinline__ uint4 pack8(float4 a, float4 b){
    union{unsigned short us[8]; uint4 v;} p;
    p.us[0]=f2us(a.x); p.us[1]=f2us(a.y); p.us[2]=f2us(a.z); p.us[3]=f2us(a.w);
    p.us[4]=f2us(b.x); p.us[5]=f2us(b.y); p.us[6]=f2us(b.z); p.us[7]=f2us(b.w);
    return p.v;
}

// ---------------------------------------------------------------------------
// prep: LDS-tiled transposes (round-6 form, separate launch — R9 proved
// inline prep + grid semaphore costs ~35 us vs ~5 us as its own dispatch).
// ---------------------------------------------------------------------------
__global__ __launch_bounds__(256) void prep_kernel(
    const float* __restrict__ Wq, const float* __restrict__ Wk,
    const float* __restrict__ Wv, const float* __restrict__ bq,
    const float* __restrict__ bk, const float* __restrict__ bv,
    const float* __restrict__ Wo,
    bf16* __restrict__ WqT, bf16* __restrict__ WkT, bf16* __restrict__ WvT,
    float* __restrict__ bqp, float* __restrict__ bkp, float* __restrict__ bvp,
    bf16* __restrict__ WoT)
{
    __shared__ float T[64][68];
    const int tid = threadIdx.x, bx = blockIdx.x;
    if (bx < 384) {
        const int mat = bx / 128, rem = bx % 128;
        const int c0 = (rem >> 5) * 64, n0 = (rem & 31) * 64;
        const float* W = (mat == 0) ? Wq : (mat == 1) ? Wk : Wv;
        bf16* WT = (mat == 0) ? WqT : (mat == 1) ? WkT : WvT;
        #pragma unroll
        for (int it = 0; it < 4; ++it) {
            int pp = tid + (it << 8);
            int cl = pp >> 4, n4 = (pp & 15) * 4;
            float4 f = *(const float4*)(W + (size_t)(c0 + cl) * 2048 + n0 + n4);
            T[cl][n4] = f.x; T[cl][n4+1] = f.y; T[cl][n4+2] = f.z; T[cl][n4+3] = f.w;
        }
        __syncthreads();
        const int h = n0 >> 8, d0 = n0 & 255;
        #pragma unroll
        for (int it = 0; it < 2; ++it) {
            int pp = tid + (it << 8);
            int j = pp >> 3, g = pp & 7;
            union{unsigned short us[8]; uint4 v;} pk;
            #pragma unroll
            for (int u = 0; u < 8; ++u) pk.us[u] = f2us(T[g*8+u][j]);
            *(uint4*)(WT + (size_t)((d0 + j) * 8 + h) * 256 + c0 + g * 8) = pk.v;
        }
    } else if (bx < 387) {
        const int mat = bx - 384;
        const float* src = (mat == 0) ? bq : (mat == 1) ? bk : bv;
        float* dst = (mat == 0) ? bqp : (mat == 1) ? bkp : bvp;
        for (int n = tid; n < 2048; n += 256)
            dst[(n & 255) * 8 + (n >> 8)] = src[n];
    } else {
        const int idx = bx - 387;
        const int k0 = (idx >> 2) * 64, c0 = (idx & 3) * 64;
        #pragma unroll
        for (int it = 0; it < 4; ++it) {
            int pp = tid + (it << 8);
            int kl = pp >> 4, c4 = (pp & 15) * 4;
            float4 f = *(const float4*)(Wo + (size_t)(k0 + kl) * 256 + c0 + c4);
            T[kl][c4] = f.x; T[kl][c4+1] = f.y; T[kl][c4+2] = f.z; T[kl][c4+3] = f.w;
        }
        __syncthreads();
        #pragma unroll
        for (int it = 0; it < 2; ++it) {
            int pp = tid + (it << 8);
            int j = pp >> 3, g = pp & 7;
            union{unsigned short us[8]; uint4 v;} pk;
            #pragma unroll
            for (int u = 0; u < 8; ++u) pk.us[u] = f2us(T[g*8+u][j]);
            *(uint4*)(WoT + (size_t)(c0 + j) * 2048 + k0 + g * 8) = pk.v;
        }
    }
}

// ---------------------------------------------------------------------------
// qkav: round-6 fused body (verified 180.6 us) with two additions:
//  - wsum emits one packed b32 per (h, d-pair) instead of two scalar u16
//    LDS writes (halves that write stream; memory layout byte-identical:
//    u is equal for the pair since d0 is even, and (d0&7)*2 / (d1&7)*2 are
//    adjacent bytes).
//  - s_setprio(1) around the MFMA clusters (T5; costless, unfalsified for
//    phase-2's heterogeneous MFMA/VALU wave mix).
// Everything else byte-identical to round 6.
// ---------------------------------------------------------------------------
__global__ __launch_bounds__(512, 2) void qkav_kernel(
    const float* __restrict__ Qin, const float* __restrict__ Kin,
    const float* __restrict__ Vin, const int* __restrict__ mask,
    const bf16* __restrict__ WqT, const bf16* __restrict__ WkT,
    const bf16* __restrict__ WvT,
    const float* __restrict__ bqp, const float* __restrict__ bkp,
    const float* __restrict__ bvp,
    const bf16* __restrict__ WoT, const float* __restrict__ bo,
    float* __restrict__ Out)
{
    __shared__ __align__(16) char smem[147456];
    // phase 1 aliases
    char* const Xq = smem;
    char* const Xk = smem + 32768;
    char* const QT = smem + 65536;
    char* const KT = smem + 106496;
    float* const RED  = (float*)smem;            // [64][68] over Xq
    float* const WLDS = (float*)(smem + 106496); // [64][68] over KT (later)
    // phase 2 aliases
    char* const Xv  = smem;
    char* const VT0 = smem + 32768;
    char* const VT1 = smem + 50176;
    char* const xS0 = smem + 67584;
    char* const xS1 = smem + 83968;

    const int tid  = threadIdx.x;
    const int wid  = tid >> 6, lane = tid & 63;
    const int quad = lane >> 4, l15 = lane & 15;
    const int tok0 = blockIdx.x * 64;
    const int t6   = tid & 63, dg = tid >> 6;

    // ---------------- phase 1: Q/K projection + scores -----------------
    #pragma unroll
    for (int it = 0; it < 4; ++it) {
        int pp = tid + (it << 9);
        int row = pp >> 5, g = pp & 31;
        const float* s = Qin + (size_t)(tok0 + row) * 256 + g * 8;
        *(uint4*)(Xq + row * 512 + ((g ^ (row & 7)) << 4)) =
            pack8(*(const float4*)s, *(const float4*)(s + 4));
        s = Kin + (size_t)(tok0 + row) * 256 + g * 8;
        *(uint4*)(Xk + row * 512 + ((g ^ (row & 7)) << 4)) =
            pack8(*(const float4*)s, *(const float4*)(s + 4));
    }
    __syncthreads();

    f32x4 sacc[4];
    #pragma unroll
    for (int p = 0; p < 4; ++p)
        #pragma unroll
        for (int i = 0; i < 4; ++i) sacc[p][i] = 0.f;

    for (int Cp = 0; Cp < 8; ++Cp) {
        f32x4 accq[4][2], acck[4][2];
        #pragma unroll
        for (int mt = 0; mt < 4; ++mt)
            #pragma unroll
            for (int nt = 0; nt < 2; ++nt)
                #pragma unroll
                for (int i = 0; i < 4; ++i) { accq[mt][nt][i] = 0.f; acck[mt][nt][i] = 0.f; }
        __builtin_amdgcn_s_setprio(1);
        #pragma unroll
        for (int Ks = 0; Ks < 8; ++Ks) {
            bf16x8 bqf[2], bkf[2];
            #pragma unroll
            for (int nt = 0; nt < 2; ++nt) {
                const size_t boff =
                    (size_t)(Cp * 256 + wid * 32 + nt * 16 + l15) * 256 + Ks * 32 + quad * 8;
                bqf[nt] = *(const bf16x8*)(WqT + boff);
                bkf[nt] = *(const bf16x8*)(WkT + boff);
            }
            #pragma unroll
            for (int mt = 0; mt < 4; ++mt) {
                int row = mt * 16 + l15;
                int G = (Ks * 4 + quad) ^ (row & 7);
                bf16x8 aq = *(const bf16x8*)(Xq + row * 512 + (G << 4));
                bf16x8 ak = *(const bf16x8*)(Xk + row * 512 + (G << 4));
                #pragma unroll
                for (int nt = 0; nt < 2; ++nt) {
                    accq[mt][nt] = MFMA16(aq, bqf[nt], accq[mt][nt]);
                    acck[mt][nt] = MFMA16(ak, bkf[nt], acck[mt][nt]);
                }
            }
        }
        __builtin_amdgcn_s_setprio(0);
        #pragma unroll
        for (int nt = 0; nt < 2; ++nt) {
            const int p2 = wid * 32 + nt * 16 + l15;
            const int rowoff = p2 * 160 + ((p2 >> 6) & 3) * 8;
            const float biq = bqp[Cp * 256 + p2];
            const float bik = bkp[Cp * 256 + p2];
            #pragma unroll
            for (int mt = 0; mt < 4; ++mt) {
                int t0 = mt * 16 + quad * 4;
                union{unsigned short us[4]; uint2 v;} pq, pk;
                #pragma unroll
                for (int i = 0; i < 4; ++i) {
                    pq.us[i] = f2us(accq[mt][nt][i] + biq);
                    pk.us[i] = f2us(acck[mt][nt][i] + bik);
                }
                *(uint2*)(QT + rowoff + t0 * 2) = pq.v;
                *(uint2*)(KT + rowoff + t0 * 2) = pk.v;
            }
        }
        __syncthreads();
        #pragma unroll
        for (int pp2 = 0; pp2 < 4; ++pp2) {
            int tq = 2 * (wid * 4 + pp2) + (l15 >> 3);
            union{unsigned short us[8]; bf16x8 v;} Aq, Bk;
            #pragma unroll
            for (int j = 0; j < 8; ++j) {
                int p2 = (quad * 8 + j) * 8 + (l15 & 7);
                int off = p2 * 160 + ((p2 >> 6) & 3) * 8 + tq * 2;
                Aq.us[j] = *(const unsigned short*)(QT + off);
                Bk.us[j] = *(const unsigned short*)(KT + off);
            }
            sacc[pp2] = MFMA16(Aq.v, Bk.v, sacc[pp2]);
        }
        __syncthreads();
    }

    // diagonal extraction -> RED[t][h*8+g]  (Xq dead, KT dead)
    if ((quad >> 1) == (l15 >> 3)) {
        #pragma unroll
        for (int pp2 = 0; pp2 < 4; ++pp2) {
            int tl = (wid * 4 + pp2) * 2 + (l15 >> 3);
            #pragma unroll
            for (int i = 0; i < 4; ++i)
                RED[tl * 68 + ((quad & 1) * 4 + i) * 8 + (l15 & 7)] = sacc[pp2][i];
        }
    }
    __syncthreads();
    // softmax: thread (tl, h) -> WLDS
    {
        const int tl = tid >> 3, hh = tid & 7;
        const int mk = mask[tok0 + tl];
        const float* r = RED + tl * 68 + hh * 8;
        float m = r[0];
        #pragma unroll
        for (int g = 1; g < 8; ++g) m = fmaxf(m, r[g]);
        float e[8], sum = 0.f;
        #pragma unroll
        for (int g = 0; g < 8; ++g) { e[g] = __expf((r[g] - m) * 0.0625f); sum += e[g]; }
        float inv = 1.f / sum;
        float o[8];
        #pragma unroll
        for (int g = 0; g < 8; ++g) o[g] = mk ? e[g] * inv : 0.125f;
        float* wp = WLDS + tl * 68 + hh * 8;
        *(float4*)wp = make_float4(o[0], o[1], o[2], o[3]);
        *(float4*)(wp + 4) = make_float4(o[4], o[5], o[6], o[7]);
    }
    __syncthreads();   // WLDS visible; RED fully read before Xv overwrite

    // ---------------- phase 2: V projection + wsum + out-proj ----------
    float wv[64];
    {
        const float* wl = WLDS + t6 * 68;
        #pragma unroll
        for (int i = 0; i < 16; ++i) {
            float4 f = *(const float4*)(wl + i * 4);
            wv[i*4] = f.x; wv[i*4+1] = f.y; wv[i*4+2] = f.z; wv[i*4+3] = f.w;
        }
    }
    #pragma unroll
    for (int it = 0; it < 4; ++it) {
        int pp = tid + (it << 9);
        int row = pp >> 5, g = pp & 31;
        const float* s = Vin + (size_t)(tok0 + row) * 256 + g * 8;
        *(uint4*)(Xv + row * 512 + ((g ^ (row & 7)) << 4)) =
            pack8(*(const float4*)s, *(const float4*)(s + 4));
    }
    __syncthreads();

    const int pll = wid * 16 + l15;

    f32x4 oacc[4][2];
    #pragma unroll
    for (int mt = 0; mt < 4; ++mt)
        #pragma unroll
        for (int nt = 0; nt < 2; ++nt)
            #pragma unroll
            for (int i = 0; i < 4; ++i) oacc[mt][nt][i] = 0.f;

    for (int p = 0; p < 18; ++p) {
        char* const VTw = (p & 1) ? VT1 : VT0;
        char* const VTr = (p & 1) ? VT0 : VT1;
        char* const xSw = (p & 1) ? xS0 : xS1;
        char* const xSr = (p & 1) ? xS1 : xS0;

        // --- stream 1: v-proj for chunk C = p ---
        if (p < 16) {
            const int C = p;
            f32x4 acc[4];
            #pragma unroll
            for (int mt = 0; mt < 4; ++mt)
                #pragma unroll
                for (int i = 0; i < 4; ++i) acc[mt][i] = 0.f;
            __builtin_amdgcn_s_setprio(1);
            #pragma unroll
            for (int Ks = 0; Ks < 8; ++Ks) {
                bf16x8 b = *(const bf16x8*)(WvT + (size_t)(C * 128 + pll) * 256 + Ks * 32 + quad * 8);
                #pragma unroll
                for (int mt = 0; mt < 4; ++mt) {
                    int row = mt * 16 + l15;
                    int G = (Ks * 4 + quad) ^ (row & 7);
                    bf16x8 a = *(const bf16x8*)(Xv + row * 512 + (G << 4));
                    acc[mt] = MFMA16(a, b, acc[mt]);
                }
            }
            __builtin_amdgcn_s_setprio(0);
            const float biv = bvp[C * 128 + pll];
            #pragma unroll
            for (int mt = 0; mt < 4; ++mt) {
                int t0 = mt * 16 + quad * 4;
                union{unsigned short us[4]; uint2 v;} pk;
                #pragma unroll
                for (int i = 0; i < 4; ++i) pk.us[i] = f2us(acc[mt][i] + biv);
                *(uint2*)(VTw + pll * 136 + t0 * 2) = pk.v;
            }
        }

        // --- stream 2: weighted sum for chunk C = p-1 (VALU pipe) ---
        // computes both d-slots (d0 even, d1 = d0+1) per h and emits one
        // packed b32: u identical for the pair ((d0>>3)==(d1>>3) since d0
        // even), byte offsets (d0&7)*2 and +2 adjacent -> layout unchanged.
        if (p >= 1 && p <= 16) {
            const int d0 = dg * 2, d1 = d0 + 1;
            float vv0[8], vv1[8];
            #pragma unroll
            for (int g = 0; g < 8; ++g) {
                vv0[g] = us2f(*(const unsigned short*)(VTr + (d0 * 8 + g) * 136 + t6 * 2));
                vv1[g] = us2f(*(const unsigned short*)(VTr + (d1 * 8 + g) * 136 + t6 * 2));
            }
            #pragma unroll
            for (int h = 0; h < 8; ++h) {
                float x0 = 0.f, x1 = 0.f;
                #pragma unroll
                for (int g = 0; g < 8; ++g) {
                    x0 = fmaf(wv[h * 8 + g], vv0[g], x0);
                    x1 = fmaf(wv[h * 8 + g], vv1[g], x1);
                }
                int u = (h * 2 + (d0 >> 3)) ^ (t6 & 15);
                unsigned pairv = (unsigned)f2us(x0) | ((unsigned)f2us(x1) << 16);
                *(unsigned*)(xSw + t6 * 256 + u * 16 + (d0 & 7) * 2) = pairv;
            }
        }

        // --- stream 3: out-proj accumulate for chunk C = p-2 ---
        if (p >= 2) {
            const int C = p - 2;
            __builtin_amdgcn_s_setprio(1);
            #pragma unroll
            for (int m = 0; m < 4; ++m) {
                const int j  = 2 * m + (quad >> 1);
                const int k0 = j * 256 + C * 16 + (quad & 1) * 8;
                bf16x8 bfr[2];
                #pragma unroll
                for (int nt = 0; nt < 2; ++nt) {
                    int c = wid * 32 + nt * 16 + l15;
                    bfr[nt] = *(const bf16x8*)(WoT + (size_t)c * 2048 + k0);
                }
                #pragma unroll
                for (int mt = 0; mt < 4; ++mt) {
                    int h = mt * 2 + (l15 >> 3);
                    int t = (l15 & 7) * 8 + j;
                    int u = (h * 2 + (quad & 1)) ^ (t & 15);
                    bf16x8 afr = *(const bf16x8*)(xSr + t * 256 + u * 16);
                    #pragma unroll
                    for (int nt = 0; nt < 2; ++nt)
                        oacc[mt][nt] = MFMA16(afr, bfr[nt], oacc[mt][nt]);
                }
            }
            __builtin_amdgcn_s_setprio(0);
        }

        __syncthreads();
    }

    // epilogue: bias + direct Out write (reference's transpose-reshape rows)
    const int b = tok0 >> 11, sg0 = (tok0 & 2047) >> 3;
    #pragma unroll
    for (int nt = 0; nt < 2; ++nt) {
        int c = wid * 32 + nt * 16 + l15;
        float bias = bo[c];
        #pragma unroll
        for (int mt = 0; mt < 4; ++mt) {
            #pragma unroll
            for (int i = 0; i < 4; ++i) {
                int rr = mt * 16 + quad * 4 + i;
                int h = rr >> 3, sgl = rr & 7;
                size_t r = ((size_t)b << 11) + h * 256 + sg0 + sgl;
                Out[r * 256 + c] = oacc[mt][nt][i] + bias;
            }
        }
    }
}

// ---------------------------------------------------------------------------
extern "C" void kernel_launch(void* const* d_in, const int* in_sizes, int n_in,
                              void* d_out, int out_size, void* d_ws, size_t ws_size,
                              hipStream_t stream) {
    const float* query = (const float*)d_in[0];
    const float* key   = (const float*)d_in[1];
    const float* value = (const float*)d_in[2];
    const int*   mask  = (const int*)  d_in[3];
    const float* Wq = (const float*)d_in[4];  const float* bq = (const float*)d_in[5];
    const float* Wk = (const float*)d_in[6];  const float* bk = (const float*)d_in[7];
    const float* Wv = (const float*)d_in[8];  const float* bv = (const float*)d_in[9];
    const float* Wo = (const float*)d_in[10]; const float* bo = (const float*)d_in[11];

    // scratch in d_ws:
    char* ws = (char*)d_ws;
    bf16*  WoT = (bf16*)ws;                    // [256 c][2048 k] bf16, 1 MB
    bf16*  WqT = (bf16*)(ws + 1048576);        // [2048][256] bf16, 1 MB each
    bf16*  WkT = (bf16*)(ws + 2097152);
    bf16*  WvT = (bf16*)(ws + 3145728);
    float* bqp = (float*)(ws + 4194304);
    float* bkp = (float*)(ws + 4202496);
    float* bvp = (float*)(ws + 4210688);

    prep_kernel<<<515, 256, 0, stream>>>(
        Wq, Wk, Wv, bq, bk, bv, Wo, WqT, WkT, WvT, bqp, bkp, bvp, WoT);
    qkav_kernel<<<256, 512, 0, stream>>>(
        query, key, value, mask, WqT, WkT, WvT, bqp, bkp, bvp, WoT, bo,
        (float*)d_out);
}

// Round 11
// 261.909 us; speedup vs baseline: 1.1213x; 1.0259x over previous
//
#include <hip/hip_runtime.h>
#include <hip/hip_bf16.h>

typedef __hip_bfloat16 bf16;
typedef short bf16x8 __attribute__((ext_vector_type(8)));
typedef float f32x4 __attribute__((ext_vector_type(4)));

#define MFMA16(a,b,c) __builtin_amdgcn_mfma_f32_16x16x32_bf16(a,b,c,0,0,0)

__device__ __forceinline__ unsigned short f2us(float x){
    union{__hip_bfloat16 h; unsigned short u;} c; c.h = __float2bfloat16(x); return c.u;
}
__device__ __forceinline__ float us2f(unsigned short u){
    union{unsigned short u; __hip_bfloat16 h;} c; c.u = u; return __bfloat162float(c.h);
}
__device__ __forceinline__ uint4 pack8(float4 a, float4 b){
    union{unsigned short us[8]; uint4 v;} p;
    p.us[0]=f2us(a.x); p.us[1]=f2us(a.y); p.us[2]=f2us(a.z); p.us[3]=f2us(a.w);
    p.us[4]=f2us(b.x); p.us[5]=f2us(b.y); p.us[6]=f2us(b.z); p.us[7]=f2us(b.w);
    return p.v;
}

// ---------------------------------------------------------------------------
// prep: LDS-tiled transposes (round-6 form, separate launch — R9 proved
// inline prep + grid semaphore costs ~35 us vs ~5 us as its own dispatch).
// ---------------------------------------------------------------------------
__global__ __launch_bounds__(256) void prep_kernel(
    const float* __restrict__ Wq, const float* __restrict__ Wk,
    const float* __restrict__ Wv, const float* __restrict__ bq,
    const float* __restrict__ bk, const float* __restrict__ bv,
    const float* __restrict__ Wo,
    bf16* __restrict__ WqT, bf16* __restrict__ WkT, bf16* __restrict__ WvT,
    float* __restrict__ bqp, float* __restrict__ bkp, float* __restrict__ bvp,
    bf16* __restrict__ WoT)
{
    __shared__ float T[64][68];
    const int tid = threadIdx.x, bx = blockIdx.x;
    if (bx < 384) {
        const int mat = bx / 128, rem = bx % 128;
        const int c0 = (rem >> 5) * 64, n0 = (rem & 31) * 64;
        const float* W = (mat == 0) ? Wq : (mat == 1) ? Wk : Wv;
        bf16* WT = (mat == 0) ? WqT : (mat == 1) ? WkT : WvT;
        #pragma unroll
        for (int it = 0; it < 4; ++it) {
            int pp = tid + (it << 8);
            int cl = pp >> 4, n4 = (pp & 15) * 4;
            float4 f = *(const float4*)(W + (size_t)(c0 + cl) * 2048 + n0 + n4);
            T[cl][n4] = f.x; T[cl][n4+1] = f.y; T[cl][n4+2] = f.z; T[cl][n4+3] = f.w;
        }
        __syncthreads();
        const int h = n0 >> 8, d0 = n0 & 255;
        #pragma unroll
        for (int it = 0; it < 2; ++it) {
            int pp = tid + (it << 8);
            int j = pp >> 3, g = pp & 7;
            union{unsigned short us[8]; uint4 v;} pk;
            #pragma unroll
            for (int u = 0; u < 8; ++u) pk.us[u] = f2us(T[g*8+u][j]);
            *(uint4*)(WT + (size_t)((d0 + j) * 8 + h) * 256 + c0 + g * 8) = pk.v;
        }
    } else if (bx < 387) {
        const int mat = bx - 384;
        const float* src = (mat == 0) ? bq : (mat == 1) ? bk : bv;
        float* dst = (mat == 0) ? bqp : (mat == 1) ? bkp : bvp;
        for (int n = tid; n < 2048; n += 256)
            dst[(n & 255) * 8 + (n >> 8)] = src[n];
    } else {
        const int idx = bx - 387;
        const int k0 = (idx >> 2) * 64, c0 = (idx & 3) * 64;
        #pragma unroll
        for (int it = 0; it < 4; ++it) {
            int pp = tid + (it << 8);
            int kl = pp >> 4, c4 = (pp & 15) * 4;
            float4 f = *(const float4*)(Wo + (size_t)(k0 + kl) * 256 + c0 + c4);
            T[kl][c4] = f.x; T[kl][c4+1] = f.y; T[kl][c4+2] = f.z; T[kl][c4+3] = f.w;
        }
        __syncthreads();
        #pragma unroll
        for (int it = 0; it < 2; ++it) {
            int pp = tid + (it << 8);
            int j = pp >> 3, g = pp & 7;
            union{unsigned short us[8]; uint4 v;} pk;
            #pragma unroll
            for (int u = 0; u < 8; ++u) pk.us[u] = f2us(T[g*8+u][j]);
            *(uint4*)(WoT + (size_t)(c0 + j) * 2048 + k0 + g * 8) = pk.v;
        }
    }
}

// ---------------------------------------------------------------------------
// qkav: round-6 fused body (verified 180.6 us) + ONE change: wsum emits one
// packed b32 per (h, d-pair) instead of two scalar u16 LDS writes (R10
// measured bank conflicts 19.0M -> 17.4M with this; layout byte-identical:
// u equal for the pair since d0 even, (d0&7)*2 / (d1&7)*2 adjacent bytes).
// setprio REMOVED — R10 regressed 180.6 -> 195 with setprio+pairing; m190
// precedent says setprio hurts lockstep barrier structures, attributing the
// regression to it. No other deltas vs round 6.
// ---------------------------------------------------------------------------
__global__ __launch_bounds__(512, 2) void qkav_kernel(
    const float* __restrict__ Qin, const float* __restrict__ Kin,
    const float* __restrict__ Vin, const int* __restrict__ mask,
    const bf16* __restrict__ WqT, const bf16* __restrict__ WkT,
    const bf16* __restrict__ WvT,
    const float* __restrict__ bqp, const float* __restrict__ bkp,
    const float* __restrict__ bvp,
    const bf16* __restrict__ WoT, const float* __restrict__ bo,
    float* __restrict__ Out)
{
    __shared__ __align__(16) char smem[147456];
    // phase 1 aliases
    char* const Xq = smem;
    char* const Xk = smem + 32768;
    char* const QT = smem + 65536;
    char* const KT = smem + 106496;
    float* const RED  = (float*)smem;            // [64][68] over Xq
    float* const WLDS = (float*)(smem + 106496); // [64][68] over KT (later)
    // phase 2 aliases
    char* const Xv  = smem;
    char* const VT0 = smem + 32768;
    char* const VT1 = smem + 50176;
    char* const xS0 = smem + 67584;
    char* const xS1 = smem + 83968;

    const int tid  = threadIdx.x;
    const int wid  = tid >> 6, lane = tid & 63;
    const int quad = lane >> 4, l15 = lane & 15;
    const int tok0 = blockIdx.x * 64;
    const int t6   = tid & 63, dg = tid >> 6;

    // ---------------- phase 1: Q/K projection + scores -----------------
    #pragma unroll
    for (int it = 0; it < 4; ++it) {
        int pp = tid + (it << 9);
        int row = pp >> 5, g = pp & 31;
        const float* s = Qin + (size_t)(tok0 + row) * 256 + g * 8;
        *(uint4*)(Xq + row * 512 + ((g ^ (row & 7)) << 4)) =
            pack8(*(const float4*)s, *(const float4*)(s + 4));
        s = Kin + (size_t)(tok0 + row) * 256 + g * 8;
        *(uint4*)(Xk + row * 512 + ((g ^ (row & 7)) << 4)) =
            pack8(*(const float4*)s, *(const float4*)(s + 4));
    }
    __syncthreads();

    f32x4 sacc[4];
    #pragma unroll
    for (int p = 0; p < 4; ++p)
        #pragma unroll
        for (int i = 0; i < 4; ++i) sacc[p][i] = 0.f;

    for (int Cp = 0; Cp < 8; ++Cp) {
        f32x4 accq[4][2], acck[4][2];
        #pragma unroll
        for (int mt = 0; mt < 4; ++mt)
            #pragma unroll
            for (int nt = 0; nt < 2; ++nt)
                #pragma unroll
                for (int i = 0; i < 4; ++i) { accq[mt][nt][i] = 0.f; acck[mt][nt][i] = 0.f; }
        #pragma unroll
        for (int Ks = 0; Ks < 8; ++Ks) {
            bf16x8 bqf[2], bkf[2];
            #pragma unroll
            for (int nt = 0; nt < 2; ++nt) {
                const size_t boff =
                    (size_t)(Cp * 256 + wid * 32 + nt * 16 + l15) * 256 + Ks * 32 + quad * 8;
                bqf[nt] = *(const bf16x8*)(WqT + boff);
                bkf[nt] = *(const bf16x8*)(WkT + boff);
            }
            #pragma unroll
            for (int mt = 0; mt < 4; ++mt) {
                int row = mt * 16 + l15;
                int G = (Ks * 4 + quad) ^ (row & 7);
                bf16x8 aq = *(const bf16x8*)(Xq + row * 512 + (G << 4));
                bf16x8 ak = *(const bf16x8*)(Xk + row * 512 + (G << 4));
                #pragma unroll
                for (int nt = 0; nt < 2; ++nt) {
                    accq[mt][nt] = MFMA16(aq, bqf[nt], accq[mt][nt]);
                    acck[mt][nt] = MFMA16(ak, bkf[nt], acck[mt][nt]);
                }
            }
        }
        #pragma unroll
        for (int nt = 0; nt < 2; ++nt) {
            const int p2 = wid * 32 + nt * 16 + l15;
            const int rowoff = p2 * 160 + ((p2 >> 6) & 3) * 8;
            const float biq = bqp[Cp * 256 + p2];
            const float bik = bkp[Cp * 256 + p2];
            #pragma unroll
            for (int mt = 0; mt < 4; ++mt) {
                int t0 = mt * 16 + quad * 4;
                union{unsigned short us[4]; uint2 v;} pq, pk;
                #pragma unroll
                for (int i = 0; i < 4; ++i) {
                    pq.us[i] = f2us(accq[mt][nt][i] + biq);
                    pk.us[i] = f2us(acck[mt][nt][i] + bik);
                }
                *(uint2*)(QT + rowoff + t0 * 2) = pq.v;
                *(uint2*)(KT + rowoff + t0 * 2) = pk.v;
            }
        }
        __syncthreads();
        #pragma unroll
        for (int pp2 = 0; pp2 < 4; ++pp2) {
            int tq = 2 * (wid * 4 + pp2) + (l15 >> 3);
            union{unsigned short us[8]; bf16x8 v;} Aq, Bk;
            #pragma unroll
            for (int j = 0; j < 8; ++j) {
                int p2 = (quad * 8 + j) * 8 + (l15 & 7);
                int off = p2 * 160 + ((p2 >> 6) & 3) * 8 + tq * 2;
                Aq.us[j] = *(const unsigned short*)(QT + off);
                Bk.us[j] = *(const unsigned short*)(KT + off);
            }
            sacc[pp2] = MFMA16(Aq.v, Bk.v, sacc[pp2]);
        }
        __syncthreads();
    }

    // diagonal extraction -> RED[t][h*8+g]  (Xq dead, KT dead)
    if ((quad >> 1) == (l15 >> 3)) {
        #pragma unroll
        for (int pp2 = 0; pp2 < 4; ++pp2) {
            int tl = (wid * 4 + pp2) * 2 + (l15 >> 3);
            #pragma unroll
            for (int i = 0; i < 4; ++i)
                RED[tl * 68 + ((quad & 1) * 4 + i) * 8 + (l15 & 7)] = sacc[pp2][i];
        }
    }
    __syncthreads();
    // softmax: thread (tl, h) -> WLDS
    {
        const int tl = tid >> 3, hh = tid & 7;
        const int mk = mask[tok0 + tl];
        const float* r = RED + tl * 68 + hh * 8;
        float m = r[0];
        #pragma unroll
        for (int g = 1; g < 8; ++g) m = fmaxf(m, r[g]);
        float e[8], sum = 0.f;
        #pragma unroll
        for (int g = 0; g < 8; ++g) { e[g] = __expf((r[g] - m) * 0.0625f); sum += e[g]; }
        float inv = 1.f / sum;
        float o[8];
        #pragma unroll
        for (int g = 0; g < 8; ++g) o[g] = mk ? e[g] * inv : 0.125f;
        float* wp = WLDS + tl * 68 + hh * 8;
        *(float4*)wp = make_float4(o[0], o[1], o[2], o[3]);
        *(float4*)(wp + 4) = make_float4(o[4], o[5], o[6], o[7]);
    }
    __syncthreads();   // WLDS visible; RED fully read before Xv overwrite

    // ---------------- phase 2: V projection + wsum + out-proj ----------
    float wv[64];
    {
        const float* wl = WLDS + t6 * 68;
        #pragma unroll
        for (int i = 0; i < 16; ++i) {
            float4 f = *(const float4*)(wl + i * 4);
            wv[i*4] = f.x; wv[i*4+1] = f.y; wv[i*4+2] = f.z; wv[i*4+3] = f.w;
        }
    }
    #pragma unroll
    for (int it = 0; it < 4; ++it) {
        int pp = tid + (it << 9);
        int row = pp >> 5, g = pp & 31;
        const float* s = Vin + (size_t)(tok0 + row) * 256 + g * 8;
        *(uint4*)(Xv + row * 512 + ((g ^ (row & 7)) << 4)) =
            pack8(*(const float4*)s, *(const float4*)(s + 4));
    }
    __syncthreads();

    const int pll = wid * 16 + l15;

    f32x4 oacc[4][2];
    #pragma unroll
    for (int mt = 0; mt < 4; ++mt)
        #pragma unroll
        for (int nt = 0; nt < 2; ++nt)
            #pragma unroll
            for (int i = 0; i < 4; ++i) oacc[mt][nt][i] = 0.f;

    for (int p = 0; p < 18; ++p) {
        char* const VTw = (p & 1) ? VT1 : VT0;
        char* const VTr = (p & 1) ? VT0 : VT1;
        char* const xSw = (p & 1) ? xS0 : xS1;
        char* const xSr = (p & 1) ? xS1 : xS0;

        // --- stream 1: v-proj for chunk C = p ---
        if (p < 16) {
            const int C = p;
            f32x4 acc[4];
            #pragma unroll
            for (int mt = 0; mt < 4; ++mt)
                #pragma unroll
                for (int i = 0; i < 4; ++i) acc[mt][i] = 0.f;
            #pragma unroll
            for (int Ks = 0; Ks < 8; ++Ks) {
                bf16x8 b = *(const bf16x8*)(WvT + (size_t)(C * 128 + pll) * 256 + Ks * 32 + quad * 8);
                #pragma unroll
                for (int mt = 0; mt < 4; ++mt) {
                    int row = mt * 16 + l15;
                    int G = (Ks * 4 + quad) ^ (row & 7);
                    bf16x8 a = *(const bf16x8*)(Xv + row * 512 + (G << 4));
                    acc[mt] = MFMA16(a, b, acc[mt]);
                }
            }
            const float biv = bvp[C * 128 + pll];
            #pragma unroll
            for (int mt = 0; mt < 4; ++mt) {
                int t0 = mt * 16 + quad * 4;
                union{unsigned short us[4]; uint2 v;} pk;
                #pragma unroll
                for (int i = 0; i < 4; ++i) pk.us[i] = f2us(acc[mt][i] + biv);
                *(uint2*)(VTw + pll * 136 + t0 * 2) = pk.v;
            }
        }

        // --- stream 2: weighted sum for chunk C = p-1 (VALU pipe) ---
        // both d-slots (d0 even, d1 = d0+1) per h, one packed b32 write.
        if (p >= 1 && p <= 16) {
            const int d0 = dg * 2, d1 = d0 + 1;
            float vv0[8], vv1[8];
            #pragma unroll
            for (int g = 0; g < 8; ++g) {
                vv0[g] = us2f(*(const unsigned short*)(VTr + (d0 * 8 + g) * 136 + t6 * 2));
                vv1[g] = us2f(*(const unsigned short*)(VTr + (d1 * 8 + g) * 136 + t6 * 2));
            }
            #pragma unroll
            for (int h = 0; h < 8; ++h) {
                float x0 = 0.f, x1 = 0.f;
                #pragma unroll
                for (int g = 0; g < 8; ++g) {
                    x0 = fmaf(wv[h * 8 + g], vv0[g], x0);
                    x1 = fmaf(wv[h * 8 + g], vv1[g], x1);
                }
                int u = (h * 2 + (d0 >> 3)) ^ (t6 & 15);
                unsigned pairv = (unsigned)f2us(x0) | ((unsigned)f2us(x1) << 16);
                *(unsigned*)(xSw + t6 * 256 + u * 16 + (d0 & 7) * 2) = pairv;
            }
        }

        // --- stream 3: out-proj accumulate for chunk C = p-2 ---
        if (p >= 2) {
            const int C = p - 2;
            #pragma unroll
            for (int m = 0; m < 4; ++m) {
                const int j  = 2 * m + (quad >> 1);
                const int k0 = j * 256 + C * 16 + (quad & 1) * 8;
                bf16x8 bfr[2];
                #pragma unroll
                for (int nt = 0; nt < 2; ++nt) {
                    int c = wid * 32 + nt * 16 + l15;
                    bfr[nt] = *(const bf16x8*)(WoT + (size_t)c * 2048 + k0);
                }
                #pragma unroll
                for (int mt = 0; mt < 4; ++mt) {
                    int h = mt * 2 + (l15 >> 3);
                    int t = (l15 & 7) * 8 + j;
                    int u = (h * 2 + (quad & 1)) ^ (t & 15);
                    bf16x8 afr = *(const bf16x8*)(xSr + t * 256 + u * 16);
                    #pragma unroll
                    for (int nt = 0; nt < 2; ++nt)
                        oacc[mt][nt] = MFMA16(afr, bfr[nt], oacc[mt][nt]);
                }
            }
        }

        __syncthreads();
    }

    // epilogue: bias + direct Out write (reference's transpose-reshape rows)
    const int b = tok0 >> 11, sg0 = (tok0 & 2047) >> 3;
    #pragma unroll
    for (int nt = 0; nt < 2; ++nt) {
        int c = wid * 32 + nt * 16 + l15;
        float bias = bo[c];
        #pragma unroll
        for (int mt = 0; mt < 4; ++mt) {
            #pragma unroll
            for (int i = 0; i < 4; ++i) {
                int rr = mt * 16 + quad * 4 + i;
                int h = rr >> 3, sgl = rr & 7;
                size_t r = ((size_t)b << 11) + h * 256 + sg0 + sgl;
                Out[r * 256 + c] = oacc[mt][nt][i] + bias;
            }
        }
    }
}

// ---------------------------------------------------------------------------
extern "C" void kernel_launch(void* const* d_in, const int* in_sizes, int n_in,
                              void* d_out, int out_size, void* d_ws, size_t ws_size,
                              hipStream_t stream) {
    const float* query = (const float*)d_in[0];
    const float* key   = (const float*)d_in[1];
    const float* value = (const float*)d_in[2];
    const int*   mask  = (const int*)  d_in[3];
    const float* Wq = (const float*)d_in[4];  const float* bq = (const float*)d_in[5];
    const float* Wk = (const float*)d_in[6];  const float* bk = (const float*)d_in[7];
    const float* Wv = (const float*)d_in[8];  const float* bv = (const float*)d_in[9];
    const float* Wo = (const float*)d_in[10]; const float* bo = (const float*)d_in[11];

    // scratch in d_ws:
    char* ws = (char*)d_ws;
    bf16*  WoT = (bf16*)ws;                    // [256 c][2048 k] bf16, 1 MB
    bf16*  WqT = (bf16*)(ws + 1048576);        // [2048][256] bf16, 1 MB each
    bf16*  WkT = (bf16*)(ws + 2097152);
    bf16*  WvT = (bf16*)(ws + 3145728);
    float* bqp = (float*)(ws + 4194304);
    float* bkp = (float*)(ws + 4202496);
    float* bvp = (float*)(ws + 4210688);

    prep_kernel<<<515, 256, 0, stream>>>(
        Wq, Wk, Wv, bq, bk, bv, Wo, WqT, WkT, WvT, bqp, bkp, bvp, WoT);
    qkav_kernel<<<256, 512, 0, stream>>>(
        query, key, value, mask, WqT, WkT, WvT, bqp, bkp, bvp, WoT, bo,
        (float*)d_out);
}